// Round 14
// baseline (484.651 us; speedup 1.0000x reference)
//
#include <hip/hip_runtime.h>
#include <math.h>

#define NROWS 262144
#define DDIM  1024
#define EEXP  64
#define NDOCS 1024
#define HB    64            // hist/scatter blocks
#define RPB   (NROWS / HB)
#define BMT   16            // rows per gemm tile
#define TPB   8             // tiles per gemm block (128 rows/block)
#define NGEMM (NROWS / (BMT * TPB))   // 2048

typedef __attribute__((ext_vector_type(8))) __bf16 bf16x8;
typedef __attribute__((ext_vector_type(4))) float  f32x4;
typedef unsigned short ushort_t;
typedef unsigned int   uint_t;

// ws layout:
//   Wf16        ushort[32*8*64*8] = 256 KB  (frag-major W for 16x16x32, hi+lo)
//   hist_slices int[HB*NDOCS]
//   sorted_rows int[NROWS]
//   offsets     int[NDOCS+1]
//   cursor      int[NDOCS]
//   pen_sum f32, uniq f32, done_count int

// ---- kernel 1: convw16 (blocks 0..511) + per-block hist (512..575) ----
// Wf16 flat index i = ((Tg*8 + eb*2 + hl)*64 + l)*8 + j
//   expert e = eb*16 + (l&15), k = Tg*32 + (l>>4)*8 + j; hl=0 -> hi bf16, 1 -> lo.
__global__ __launch_bounds__(256) void conv_hist_kernel(const float* __restrict__ Wg,
                                                        ushort_t* __restrict__ Wf,
                                                        const int* __restrict__ idx,
                                                        int* __restrict__ hist_slices) {
    if (blockIdx.x < 512) {
        const int i  = blockIdx.x * 256 + threadIdx.x;   // 0..131071
        const int j  = i & 7;
        const int l  = (i >> 3) & 63;
        const int hl = (i >> 9) & 1;
        const int eb = (i >> 10) & 3;
        const int Tg = i >> 12;
        const int e  = eb * 16 + (l & 15);
        const int k  = Tg * 32 + (l >> 4) * 8 + j;
        const float wv = Wg[e * DDIM + k];
        const uint_t b = __float_as_uint(wv);
        ushort_t out;
        if (hl == 0) {
            out = (ushort_t)(b >> 16);
        } else {
            const float lov = wv - __uint_as_float(b & 0xFFFF0000u);
            out = (ushort_t)(__float_as_uint(lov) >> 16);
        }
        Wf[i] = out;
    } else {
        __shared__ int lh[NDOCS];
        const int bh = blockIdx.x - 512;
        const int t  = threadIdx.x;
        for (int i = t; i < NDOCS; i += 256) lh[i] = 0;
        __syncthreads();
        const int base = bh * RPB;
        for (int i = t; i < RPB; i += 256) atomicAdd(&lh[idx[base + i]], 1);
        __syncthreads();
        for (int i = t; i < NDOCS; i += 256) hist_slices[bh * NDOCS + i] = lh[i];
    }
}

// ---- kernel 2: reduce slices -> scan -> offsets/cursor; zero scalars ----
__global__ __launch_bounds__(1024) void scan_kernel(const int* __restrict__ hist_slices,
                                                    int* __restrict__ offsets,
                                                    int* __restrict__ cursor,
                                                    float* __restrict__ pen_sum,
                                                    float* __restrict__ uniq,
                                                    int* __restrict__ done_count) {
    __shared__ int sbuf[NDOCS];
    const int t = threadIdx.x;
    int my = 0;
    #pragma unroll 4
    for (int b = 0; b < HB; ++b) my += hist_slices[b * NDOCS + t];
    sbuf[t] = my;
    __syncthreads();
    for (int off = 1; off < NDOCS; off <<= 1) {
        int add = (t >= off) ? sbuf[t - off] : 0;
        __syncthreads();
        sbuf[t] += add;
        __syncthreads();
    }
    const int excl = sbuf[t] - my;
    offsets[t] = excl;
    cursor[t]  = excl;
    if (t == NDOCS - 1) offsets[NDOCS] = sbuf[t];
    if (t == 0) { pen_sum[0] = 0.0f; uniq[0] = 0.0f; done_count[0] = 0; }
}

__device__ __forceinline__ void gl2lds16(const float* g, float* l) {
    __builtin_amdgcn_global_load_lds(
        (const __attribute__((address_space(1))) void*)g,
        (__attribute__((address_space(3))) void*)l,
        16, 0, 0);
}

#define VMCNT(N)  asm volatile("s_waitcnt vmcnt(" #N ")" ::: "memory")
#define LGKM0()   asm volatile("s_waitcnt lgkmcnt(0)" ::: "memory")
#define BAR()     do { __builtin_amdgcn_s_barrier(); asm volatile("" ::: "memory"); } while (0)

// ---- kernel 3: gemm+softmax (blocks HB..HB+2047) + scatter (blocks 0..63) ----
// 16-row tiles, 1 KB-contiguous-per-row staging (64 lanes x 16B per gl2lds).
// Block: 4 waves; wave w = experts 16w..16w+15 via 16x16x32 MFMA (R2-verified
// fragment conventions). xs: block-shared 2 x 16KB dbuf (16 rows x 256 f32,
// 16B-unit XOR swizzle u^=row). W frag-major from L2 into 16 named regs/phase.
// One barrier/phase; counted vmcnt keeps next stage in flight. 4 blocks/CU.
__global__ __launch_bounds__(256, 4) void gemm_scatter_kernel(
    const float*    __restrict__ x,
    const ushort_t* __restrict__ Wf,
    const int*      __restrict__ idx,
    int*            __restrict__ cursor,
    int*            __restrict__ sorted_rows,
    float*          __restrict__ w_out)
{
    __shared__ float xs[2][BMT * 256];   // 2 x 16 KB
    __shared__ float lsm[BMT * 68];      // 4.25 KB logits for cross-wave softmax

    if (blockIdx.x < HB) {
        // ---- scatter: block-range reservation, <=NDOCS global atomics ----
        int* lh    = (int*)&xs[0][0];
        int* lbase = lh + NDOCS;
        int* lc    = lbase + NDOCS;
        const int bh = blockIdx.x;
        const int t  = threadIdx.x;
        for (int i = t; i < NDOCS; i += 256) { lh[i] = 0; lc[i] = 0; }
        __syncthreads();
        const int base = bh * RPB;
        for (int i = t; i < RPB; i += 256) atomicAdd(&lh[idx[base + i]], 1);
        __syncthreads();
        for (int i = t; i < NDOCS; i += 256) {
            const int c = lh[i];
            if (c) lbase[i] = atomicAdd(&cursor[i], c);
        }
        __syncthreads();
        for (int i = t; i < RPB; i += 256) {
            const int r = base + i;
            const int d = idx[r];
            const int p = atomicAdd(&lc[d], 1);
            sorted_rows[lbase[d] + p] = r;
        }
        return;
    }

    const int gb   = blockIdx.x - HB;       // 0..2047
    const int t    = threadIdx.x;
    const int w    = t >> 6;
    const int l    = t & 63;
    const int al16 = l & 15;    // A-row / B-col / D-col
    const int g2   = l >> 4;    // k-group 0..3
    const size_t br = (size_t)gb * (BMT * TPB);
    const int s0   = gb & 3;    // k-super rotation

    f32x4 acc = {0.f, 0.f, 0.f, 0.f};
    bf16x8 wh0, wl0, wh1, wl1, wh2, wl2, wh3, wl3, wh4, wl4, wh5, wl5, wh6, wl6, wh7, wl7;

    union u8b { uint_t u[4]; bf16x8 v; };

#define LWT(T2, WH, WL) do {                                                           \
        const ushort_t* p_ = Wf + ((size_t)((T2) * 8 + w * 2) * 64 + l) * 8;           \
        WH = *(const bf16x8*)p_;                                                       \
        WL = *(const bf16x8*)(p_ + 512);                                               \
    } while (0)

#define LOAD_W_ALL(S) do {                                                             \
        LWT((S)*8 + 0, wh0, wl0); LWT((S)*8 + 1, wh1, wl1);                            \
        LWT((S)*8 + 2, wh2, wl2); LWT((S)*8 + 3, wh3, wl3);                            \
        LWT((S)*8 + 4, wh4, wl4); LWT((S)*8 + 5, wh5, wl5);                            \
        LWT((S)*8 + 6, wh6, wl6); LWT((S)*8 + 7, wh7, wl7);                            \
    } while (0)

// Stage phase P: rows tile(P)*16 .. +15, k-window super(P)*256 .. +255.
// Wave w stages rows 4w..4w+3; one gl2lds = 1 KB contiguous of one row.
// LDS unit u holds global unit (u ^ row) -> read with u ^ row (involution).
#define STAGE(BUF, P) do {                                                             \
        const int rb_ = ((P) >> 2) * BMT;                                              \
        const int kb_ = ((s0 + ((P) & 3)) & 3) * 256;                                  \
        float* xb_ = &xs[BUF][0];                                                      \
        _Pragma("unroll")                                                              \
        for (int i_ = 0; i_ < 4; ++i_) {                                               \
            const int rl_ = w * 4 + i_;                                                \
            const float* gp_ = x + (br + rb_ + rl_) * (size_t)DDIM + kb_ + ((l ^ rl_) * 4); \
            gl2lds16(gp_, xb_ + rl_ * 256);                                            \
        } } while (0)

#define SPLIT8(A, B, AH, AL) do {                                                      \
        const float av_[8] = {A.x, A.y, A.z, A.w, B.x, B.y, B.z, B.w};                 \
        _Pragma("unroll")                                                              \
        for (int p_ = 0; p_ < 4; ++p_) {                                               \
            const uint_t b0_ = __float_as_uint(av_[2 * p_]);                           \
            const uint_t b1_ = __float_as_uint(av_[2 * p_ + 1]);                       \
            AH.u[p_] = (b0_ >> 16) | (b1_ & 0xFFFF0000u);                              \
            const float l0_ = av_[2 * p_]     - __uint_as_float(b0_ & 0xFFFF0000u);    \
            const float l1_ = av_[2 * p_ + 1] - __uint_as_float(b1_ & 0xFFFF0000u);    \
            AL.u[p_] = (__float_as_uint(l0_) >> 16) | (__float_as_uint(l1_) & 0xFFFF0000u); \
        } } while (0)

#define KTILE(XB, TL, WH, WL) do {                                                     \
        const int u0_ = ((TL) * 8 + g2 * 2)     ^ al16;                                \
        const int u1_ = ((TL) * 8 + g2 * 2 + 1) ^ al16;                                \
        const float4 a0_ = *(const float4*)&(XB)[al16 * 256 + u0_ * 4];                \
        const float4 a1_ = *(const float4*)&(XB)[al16 * 256 + u1_ * 4];                \
        u8b ah_, al_;                                                                  \
        SPLIT8(a0_, a1_, ah_, al_);                                                    \
        acc = __builtin_amdgcn_mfma_f32_16x16x32_bf16(ah_.v, WH, acc, 0, 0, 0);        \
        acc = __builtin_amdgcn_mfma_f32_16x16x32_bf16(ah_.v, WL, acc, 0, 0, 0);        \
        acc = __builtin_amdgcn_mfma_f32_16x16x32_bf16(al_.v, WH, acc, 0, 0, 0);        \
    } while (0)

// Epilogue for tile TAU: logits -> lsm, cross-wave softmax, coalesced row writes.
// D-layout (16x16, R2-verified): row = g2*4 + r, col = al16; expert = w*16 + al16.
#define EPILOGUE(TAU) do {                                                             \
        _Pragma("unroll")                                                              \
        for (int r_ = 0; r_ < 4; ++r_)                                                 \
            lsm[(g2 * 4 + r_) * 68 + w * 16 + al16] = acc[r_];                         \
        LGKM0(); BAR();                                                                \
        const size_t rowg0_ = br + (size_t)(TAU) * BMT + w * 4;                        \
        _Pragma("unroll")                                                              \
        for (int rr_ = 0; rr_ < 4; ++rr_) {                                            \
            const float v_ = lsm[(w * 4 + rr_) * 68 + l];                              \
            float m_ = v_;                                                             \
            m_ = fmaxf(m_, __shfl_xor(m_, 1));                                         \
            m_ = fmaxf(m_, __shfl_xor(m_, 2));                                         \
            m_ = fmaxf(m_, __shfl_xor(m_, 4));                                         \
            m_ = fmaxf(m_, __shfl_xor(m_, 8));                                         \
            m_ = fmaxf(m_, __shfl_xor(m_, 16));                                        \
            m_ = fmaxf(m_, __shfl_xor(m_, 32));                                        \
            const float e_ = __expf(v_ - m_);                                          \
            float sden_ = e_;                                                          \
            sden_ += __shfl_xor(sden_, 1);                                             \
            sden_ += __shfl_xor(sden_, 2);                                             \
            sden_ += __shfl_xor(sden_, 4);                                             \
            sden_ += __shfl_xor(sden_, 8);                                             \
            sden_ += __shfl_xor(sden_, 16);                                            \
            sden_ += __shfl_xor(sden_, 32);                                            \
            w_out[(rowg0_ + rr_) * EEXP + l] = e_ / sden_;                             \
        }                                                                              \
        acc = (f32x4){0.f, 0.f, 0.f, 0.f};                                             \
    } while (0)

    // ---- prologue: stage phase 0 (4 ops/wave) ----
    STAGE(0, 0);

    // ---- phases 0..30: [W16] vm16 BAR [stage4] vm12 kt0-3 vm4 kt4-7 (epi at q==3) ----
    #pragma unroll 1
    for (int P = 0; P < 31; ++P) {
        const int S = (s0 + (P & 3)) & 3;
        const float* xb = &xs[P & 1][0];
        LOAD_W_ALL(S);
        VMCNT(16);             // my stage(P) landed (keeps W16)
        BAR();                 // x(P) complete; all waves done reading other buf
        STAGE((P & 1) ^ 1, P + 1);
        VMCNT(12);             // W tiles 0..3 landed (keeps W8 + stage4)
        KTILE(xb, 0, wh0, wl0);
        KTILE(xb, 1, wh1, wl1);
        KTILE(xb, 2, wh2, wl2);
        KTILE(xb, 3, wh3, wl3);
        VMCNT(4);              // all W landed (keeps stage4)
        KTILE(xb, 4, wh4, wl4);
        KTILE(xb, 5, wh5, wl5);
        KTILE(xb, 6, wh6, wl6);
        KTILE(xb, 7, wh7, wl7);
        if ((P & 3) == 3) EPILOGUE(P >> 2);
    }
    // ---- phase 31 (peeled: no next stage) ----
    {
        const int S = (s0 + 3) & 3;
        const float* xb = &xs[1][0];
        LOAD_W_ALL(S);
        VMCNT(16);
        BAR();
        VMCNT(8);
        KTILE(xb, 0, wh0, wl0);
        KTILE(xb, 1, wh1, wl1);
        KTILE(xb, 2, wh2, wl2);
        KTILE(xb, 3, wh3, wl3);
        VMCNT(0);
        KTILE(xb, 4, wh4, wl4);
        KTILE(xb, 5, wh5, wl5);
        KTILE(xb, 6, wh6, wl6);
        KTILE(xb, 7, wh7, wl7);
        EPILOGUE(7);
    }
#undef LWT
#undef LOAD_W_ALL
#undef STAGE
#undef SPLIT8
#undef KTILE
#undef EPILOGUE
}

// ---- kernel 4: segsum + last-block finalize ----
__global__ __launch_bounds__(256) void segsum_final_kernel(
    const float* __restrict__ w,
    const int*   __restrict__ sorted_rows,
    const int*   __restrict__ offsets,
    float*       __restrict__ pen_sum,
    float*       __restrict__ uniq,
    int*         __restrict__ done_count,
    float*       __restrict__ pen_out)
{
    __shared__ int rows_s[512];
    __shared__ float ls1[4][64], ls2[4][64];

    const int d  = blockIdx.x;
    const int t  = threadIdx.x;
    const int e  = t & 63;
    const int rg = t >> 6;
    const int start = offsets[d];
    const int end   = offsets[d + 1];
    const int n     = end - start;

    for (int i = t; i < n && i < 512; i += 256) rows_s[i] = sorted_rows[start + i];
    __syncthreads();

    float s1 = 0.0f, s2 = 0.0f;
    for (int i = rg; i < n; i += 4) {
        const int row = (i < 512) ? rows_s[i] : sorted_rows[start + i];
        const float v = w[(size_t)row * EEXP + e];
        s1 += v;
        s2 += v * v;
    }

    ls1[rg][e] = s1;
    ls2[rg][e] = s2;
    __syncthreads();

    if (t < 64) {
        const float a = ls1[0][e] + ls1[1][e] + ls1[2][e] + ls1[3][e];
        const float b = ls2[0][e] + ls2[1][e] + ls2[2][e] + ls2[3][e];
        const float safe = fmaxf((float)n, 1.0f);
        float contrib = b - a * a / safe;
        #pragma unroll
        for (int off = 32; off > 0; off >>= 1)
            contrib += __shfl_down(contrib, off);
        if (e == 0) {
            if (n > 1) atomicAdd(pen_sum, contrib / (safe * (float)EEXP));
            if (n > 0) atomicAdd(uniq, 1.0f);
        }
    }
    __syncthreads();
    if (t == 0) {
        __threadfence();
        const int prev = atomicAdd(done_count, 1);
        if (prev == NDOCS - 1) {
            __threadfence();
            pen_out[0] = pen_sum[0] / uniq[0];
        }
    }
}

extern "C" void kernel_launch(void* const* d_in, const int* in_sizes, int n_in,
                              void* d_out, int out_size, void* d_ws, size_t ws_size,
                              hipStream_t stream) {
    const float* x   = (const float*)d_in[0];
    const int*   idx = (const int*)d_in[1];
    const float* Wg  = (const float*)d_in[2];

    float* out   = (float*)d_out;
    float* w_out = out;                                  // NROWS*EEXP floats
    float* pen   = out + (size_t)NROWS * EEXP;           // 1 float

    ushort_t* Wf     = (ushort_t*)d_ws;                  // 131072 ushorts
    int* hist_slices = (int*)(Wf + 131072);              // HB*NDOCS ints
    int* sorted_rows = hist_slices + HB * NDOCS;
    int* offsets     = sorted_rows + NROWS;
    int* cursor      = offsets + NDOCS + 1;
    float* pen_sum   = (float*)(cursor + NDOCS);
    float* uniq      = pen_sum + 1;
    int* done_count  = (int*)(uniq + 1);

    conv_hist_kernel<<<512 + HB, 256, 0, stream>>>(Wg, Wf, idx, hist_slices);
    scan_kernel<<<1, 1024, 0, stream>>>(hist_slices, offsets, cursor, pen_sum, uniq, done_count);
    gemm_scatter_kernel<<<HB + NGEMM, 256, 0, stream>>>(x, Wf, idx, cursor, sorted_rows, w_out);
    segsum_final_kernel<<<NDOCS, 256, 0, stream>>>(w_out, sorted_rows, offsets, pen_sum, uniq, done_count, pen);
}

// Round 15
// 338.367 us; speedup vs baseline: 1.4323x; 1.4323x over previous
//
#include <hip/hip_runtime.h>
#include <math.h>

#define NROWS 262144
#define DDIM  1024
#define EEXP  64
#define NDOCS 1024
#define BM    128
#define HB    64            // hist/scatter blocks
#define RPB   (NROWS / HB)  // rows per hist/scatter block
#define NGEMM (NROWS / BM)  // 2048

typedef __attribute__((ext_vector_type(8)))  __bf16 bf16x8;
typedef __attribute__((ext_vector_type(16))) float  f32x16;
typedef unsigned short ushort_t;
typedef unsigned int   uint_t;

// ws layout:
//   Wf          ushort[32*8*64*8]   (256 KB fragment-major W, hi+lo)
//   hist_slices int[HB*NDOCS]
//   sorted_rows int[NROWS]
//   offsets     int[NDOCS+1]
//   cursor      int[NDOCS]
//   pen_sum f32, uniq f32, done_count int

// ---- kernel 1: convw (blocks 0..511) + per-block hist (blocks 512..575) ----
__global__ __launch_bounds__(256) void conv_hist_kernel(const float* __restrict__ Wg,
                                                        ushort_t* __restrict__ Wf,
                                                        const int* __restrict__ idx,
                                                        int* __restrict__ hist_slices) {
    if (blockIdx.x < 512) {
        const int i = blockIdx.x * 256 + threadIdx.x;   // 0 .. 131071
        const int j = i & 7;
        const int l = (i >> 3) & 63;
        const int f = (i >> 9) & 7;
        const int T = i >> 12;
        const int cl = l & 31;
        const int hi = l >> 5;
        const int e  = cl + 32 * ((f >> 1) & 1);
        const int k  = T * 32 + 16 * (f & 1) + 8 * hi + j;
        const float wv = Wg[e * DDIM + k];
        const uint_t b = __float_as_uint(wv);
        ushort_t out;
        if (f < 4) {
            out = (ushort_t)(b >> 16);
        } else {
            const float lov = wv - __uint_as_float(b & 0xFFFF0000u);
            out = (ushort_t)(__float_as_uint(lov) >> 16);
        }
        Wf[i] = out;
    } else {
        __shared__ int lh[NDOCS];
        const int bh = blockIdx.x - 512;
        const int t  = threadIdx.x;
        for (int i = t; i < NDOCS; i += 256) lh[i] = 0;
        __syncthreads();
        const int base = bh * RPB;
        for (int i = t; i < RPB; i += 256) atomicAdd(&lh[idx[base + i]], 1);
        __syncthreads();
        for (int i = t; i < NDOCS; i += 256) hist_slices[bh * NDOCS + i] = lh[i];
    }
}

// ---- kernel 2: reduce slices -> scan -> offsets/cursor; zero scalars ----
__global__ __launch_bounds__(1024) void scan_kernel(const int* __restrict__ hist_slices,
                                                    int* __restrict__ offsets,
                                                    int* __restrict__ cursor,
                                                    float* __restrict__ pen_sum,
                                                    float* __restrict__ uniq,
                                                    int* __restrict__ done_count) {
    __shared__ int sbuf[NDOCS];
    const int t = threadIdx.x;
    int my = 0;
    #pragma unroll 4
    for (int b = 0; b < HB; ++b) my += hist_slices[b * NDOCS + t];
    sbuf[t] = my;
    __syncthreads();
    for (int off = 1; off < NDOCS; off <<= 1) {
        int add = (t >= off) ? sbuf[t - off] : 0;
        __syncthreads();
        sbuf[t] += add;
        __syncthreads();
    }
    const int excl = sbuf[t] - my;
    offsets[t] = excl;
    cursor[t]  = excl;
    if (t == NDOCS - 1) offsets[NDOCS] = sbuf[t];
    if (t == 0) { pen_sum[0] = 0.0f; uniq[0] = 0.0f; done_count[0] = 0; }
}

__device__ __forceinline__ void gl2lds16(const float* g, float* l) {
    __builtin_amdgcn_global_load_lds(
        (const __attribute__((address_space(1))) void*)g,
        (__attribute__((address_space(3))) void*)l,
        16, 0, 0);
}

#define VMCNT(N)  asm volatile("s_waitcnt vmcnt(" #N ")" ::: "memory")

// ---- kernel 3: barrier-free gemm+softmax (blocks 0..2047) + scatter (2048..2111) ----
// 64-k supers, 256 B/row granule, wave-private LDS dbuf, frag-major W from L2,
// zero barriers, counted vmcnt, per-wave k-phase rotation (s0=(5b+w)&15).
struct WT { bf16x8 h00, h01, h10, h11, m00, m01, m10, m11; };

__global__ __launch_bounds__(256, 2) void gemm_scatter_kernel(
    const float*    __restrict__ x,
    const ushort_t* __restrict__ Wf,
    const int*      __restrict__ idx,
    int*            __restrict__ cursor,
    int*            __restrict__ sorted_rows,
    float*          __restrict__ w_out)
{
    __shared__ float xs[2][8192];   // 64 KB: 2 bufs x (4 waves x 2048 floats private)

    if (blockIdx.x >= NGEMM) {
        // ---- scatter: block-range reservation, <=NDOCS global atomics ----
        int* lh    = (int*)&xs[0][0];
        int* lbase = lh + NDOCS;
        int* lc    = lbase + NDOCS;
        const int bh = blockIdx.x - NGEMM;
        const int t  = threadIdx.x;
        for (int i = t; i < NDOCS; i += 256) { lh[i] = 0; lc[i] = 0; }
        __syncthreads();
        const int base = bh * RPB;
        for (int i = t; i < RPB; i += 256) atomicAdd(&lh[idx[base + i]], 1);
        __syncthreads();
        for (int i = t; i < NDOCS; i += 256) {
            const int c = lh[i];
            if (c) lbase[i] = atomicAdd(&cursor[i], c);
        }
        __syncthreads();
        for (int i = t; i < RPB; i += 256) {
            const int r = base + i;
            const int d = idx[r];
            const int p = atomicAdd(&lc[d], 1);
            sorted_rows[lbase[d] + p] = r;
        }
        return;
    }

    const int t   = threadIdx.x;
    const int w   = t >> 6;
    const int l   = t & 63;
    const int cl  = l & 31;     // A-row-in-wave-tile / B-col / D-col
    const int hi  = l >> 5;     // k-half selector
    const size_t br = (size_t)blockIdx.x * BM;

    f32x16 acc0 = {};
    f32x16 acc1 = {};
    WT wA, wB;

    union u8b { uint_t u[4]; bf16x8 v; };

#define LOAD_WF(DST, T2) do {                                                          \
        const ushort_t* p_ = Wf + ((size_t)(T2) * 8 * 64 + l) * 8;                     \
        DST.h00 = *(const bf16x8*)(p_ + 0 * 512);                                      \
        DST.h01 = *(const bf16x8*)(p_ + 1 * 512);                                      \
        DST.h10 = *(const bf16x8*)(p_ + 2 * 512);                                      \
        DST.h11 = *(const bf16x8*)(p_ + 3 * 512);                                      \
        DST.m00 = *(const bf16x8*)(p_ + 4 * 512);                                      \
        DST.m01 = *(const bf16x8*)(p_ + 5 * 512);                                      \
        DST.m10 = *(const bf16x8*)(p_ + 6 * 512);                                      \
        DST.m11 = *(const bf16x8*)(p_ + 7 * 512);                                      \
    } while (0)

// Stage one 64-k super for this wave: 8 gl2lds, each covering 4 rows x 256 B.
// Row r's 64 floats live at float-offset (r>>2)*256 + (r&3)*64, 16B-unit
// position u ^ (r&15) (pre-swizzled via the global source address).
#define STAGE_X2(BUF, SUP) do {                                                        \
        float* xb_ = &xs[BUF][w * 2048];                                               \
        _Pragma("unroll")                                                              \
        for (int i_ = 0; i_ < 8; ++i_) {                                               \
            const int row_ = i_ * 4 + (l >> 4);                                        \
            const int u_   = (l & 15) ^ (row_ & 15);                                   \
            const float* gp_ = x + (br + w * 32 + row_) * DDIM + (SUP) * 64 + u_ * 4;  \
            gl2lds16(gp_, xb_ + i_ * 256);                                             \
        } } while (0)

#define SPLIT8(A, B, AH, AL) do {                                                      \
        const float av_[8] = {A.x, A.y, A.z, A.w, B.x, B.y, B.z, B.w};                 \
        _Pragma("unroll")                                                              \
        for (int p_ = 0; p_ < 4; ++p_) {                                               \
            const uint_t b0_ = __float_as_uint(av_[2 * p_]);                           \
            const uint_t b1_ = __float_as_uint(av_[2 * p_ + 1]);                       \
            AH.u[p_] = (b0_ >> 16) | (b1_ & 0xFFFF0000u);                              \
            const float l0_ = av_[2 * p_]     - __uint_as_float(b0_ & 0xFFFF0000u);    \
            const float l1_ = av_[2 * p_ + 1] - __uint_as_float(b1_ & 0xFFFF0000u);    \
            AL.u[p_] = (__float_as_uint(l0_) >> 16) | (__float_as_uint(l1_) & 0xFFFF0000u); \
        } } while (0)

// Compute 32-k tile TT (0/1) of buffer BUF with W set WV.
#define COMPUTE(BUF, TT, WV) do {                                                      \
        const float* xb_ = &xs[BUF][w * 2048];                                         \
        const int blk_ = (cl >> 2) * 256 + (cl & 3) * 64;                              \
        const int ku_  = (TT) * 8 + hi * 2;                                            \
        const int sw_  = cl & 15;                                                      \
        const float4 a0_ = *(const float4*)&xb_[blk_ + (((ku_ + 0) ^ sw_) * 4)];       \
        const float4 a1_ = *(const float4*)&xb_[blk_ + (((ku_ + 1) ^ sw_) * 4)];       \
        const float4 a2_ = *(const float4*)&xb_[blk_ + (((ku_ + 4) ^ sw_) * 4)];       \
        const float4 a3_ = *(const float4*)&xb_[blk_ + (((ku_ + 5) ^ sw_) * 4)];       \
        u8b ah0, al0, ah1, al1;                                                        \
        SPLIT8(a0_, a1_, ah0, al0);                                                    \
        SPLIT8(a2_, a3_, ah1, al1);                                                    \
        acc0 = __builtin_amdgcn_mfma_f32_32x32x16_bf16(ah0.v, WV.h00, acc0, 0, 0, 0);  \
        acc1 = __builtin_amdgcn_mfma_f32_32x32x16_bf16(ah0.v, WV.h10, acc1, 0, 0, 0);  \
        acc0 = __builtin_amdgcn_mfma_f32_32x32x16_bf16(ah0.v, WV.m00, acc0, 0, 0, 0);  \
        acc1 = __builtin_amdgcn_mfma_f32_32x32x16_bf16(ah0.v, WV.m10, acc1, 0, 0, 0);  \
        acc0 = __builtin_amdgcn_mfma_f32_32x32x16_bf16(al0.v, WV.h00, acc0, 0, 0, 0);  \
        acc1 = __builtin_amdgcn_mfma_f32_32x32x16_bf16(al0.v, WV.h10, acc1, 0, 0, 0);  \
        acc0 = __builtin_amdgcn_mfma_f32_32x32x16_bf16(ah1.v, WV.h01, acc0, 0, 0, 0);  \
        acc1 = __builtin_amdgcn_mfma_f32_32x32x16_bf16(ah1.v, WV.h11, acc1, 0, 0, 0);  \
        acc0 = __builtin_amdgcn_mfma_f32_32x32x16_bf16(ah1.v, WV.m01, acc0, 0, 0, 0);  \
        acc1 = __builtin_amdgcn_mfma_f32_32x32x16_bf16(ah1.v, WV.m11, acc1, 0, 0, 0);  \
        acc0 = __builtin_amdgcn_mfma_f32_32x32x16_bf16(al1.v, WV.h01, acc0, 0, 0, 0);  \
        acc1 = __builtin_amdgcn_mfma_f32_32x32x16_bf16(al1.v, WV.h11, acc1, 0, 0, 0);  \
    } while (0)

    // Per-wave k-phase rotation: start super s0, sweep cyclically mod 16.
    const int s0  = ((int)blockIdx.x * 5 + w) & 15;
    const int sP1 = (s0 + 1) & 15;

    // ---- prologue: W(2s0)->A, X(s0)->buf0, W(2s0+1)->B, X(s0+1)->buf1 ----
    LOAD_WF(wA, 2 * s0);
    STAGE_X2(0, s0);
    LOAD_WF(wB, 2 * s0 + 1);
    STAGE_X2(1, sP1);
    VMCNT(16);                 // keep [wB, X(s0+1)]: wA + X(s0) landed
    COMPUTE(0, 0, wA);
    LOAD_WF(wA, 2 * sP1);
    VMCNT(16);                 // keep [X(s0+1), wA]: wB landed
    COMPUTE(0, 1, wB);

    // ---- steady supers S = 1..14 (cyclic indices) ----
    #pragma unroll 1
    for (int S = 1; S < 15; ++S) {
        const int cb   = S & 1;
        const int scur = (s0 + S) & 15;
        const int snxt = (s0 + S + 1) & 15;
        LOAD_WF(wB, 2 * scur + 1);
        STAGE_X2(cb ^ 1, snxt);
        VMCNT(16);             // keep [wB, X(next)]: X(cur) + wA landed
        COMPUTE(cb, 0, wA);
        LOAD_WF(wA, 2 * snxt);
        VMCNT(16);             // keep [X(next), wA]: wB landed
        COMPUTE(cb, 1, wB);
    }
    // ---- last super (cb=1): no further x ----
    {
        const int slast = (s0 + 15) & 15;
        LOAD_WF(wB, 2 * slast + 1);
        VMCNT(8);              // keep [wB]: X(last) + wA landed
        COMPUTE(1, 0, wA);
        VMCNT(0);
        COMPUTE(1, 1, wB);
    }

    // In-register softmax. D-layout: col = lane&31, row = (r&3) + 8*(r>>2) + 4*hi.
    const size_t orow_base = br + (size_t)w * 32;
    #pragma unroll
    for (int r = 0; r < 16; ++r) {
        const int row = (r & 3) + 8 * (r >> 2) + 4 * hi;
        const float v0 = acc0[r];
        const float v1 = acc1[r];
        float m = fmaxf(v0, v1);
        m = fmaxf(m, __shfl_xor(m, 1));
        m = fmaxf(m, __shfl_xor(m, 2));
        m = fmaxf(m, __shfl_xor(m, 4));
        m = fmaxf(m, __shfl_xor(m, 8));
        m = fmaxf(m, __shfl_xor(m, 16));
        const float e0 = __expf(v0 - m);
        const float e1 = __expf(v1 - m);
        float s = e0 + e1;
        s += __shfl_xor(s, 1);
        s += __shfl_xor(s, 2);
        s += __shfl_xor(s, 4);
        s += __shfl_xor(s, 8);
        s += __shfl_xor(s, 16);
        const float inv = 1.0f / s;
        float* wo = w_out + (orow_base + row) * EEXP;
        wo[cl]      = e0 * inv;
        wo[32 + cl] = e1 * inv;
    }
#undef LOAD_WF
#undef STAGE_X2
#undef SPLIT8
#undef COMPUTE
}

// ---- kernel 4: segsum + last-block finalize ----
__global__ __launch_bounds__(256) void segsum_final_kernel(
    const float* __restrict__ w,
    const int*   __restrict__ sorted_rows,
    const int*   __restrict__ offsets,
    float*       __restrict__ pen_sum,
    float*       __restrict__ uniq,
    int*         __restrict__ done_count,
    float*       __restrict__ pen_out)
{
    __shared__ int rows_s[512];
    __shared__ float ls1[4][64], ls2[4][64];

    const int d  = blockIdx.x;
    const int t  = threadIdx.x;
    const int e  = t & 63;
    const int rg = t >> 6;
    const int start = offsets[d];
    const int end   = offsets[d + 1];
    const int n     = end - start;

    for (int i = t; i < n && i < 512; i += 256) rows_s[i] = sorted_rows[start + i];
    __syncthreads();

    float s1 = 0.0f, s2 = 0.0f;
    for (int i = rg; i < n; i += 4) {
        const int row = (i < 512) ? rows_s[i] : sorted_rows[start + i];
        const float v = w[(size_t)row * EEXP + e];
        s1 += v;
        s2 += v * v;
    }

    ls1[rg][e] = s1;
    ls2[rg][e] = s2;
    __syncthreads();

    if (t < 64) {
        const float a = ls1[0][e] + ls1[1][e] + ls1[2][e] + ls1[3][e];
        const float b = ls2[0][e] + ls2[1][e] + ls2[2][e] + ls2[3][e];
        const float safe = fmaxf((float)n, 1.0f);
        float contrib = b - a * a / safe;
        #pragma unroll
        for (int off = 32; off > 0; off >>= 1)
            contrib += __shfl_down(contrib, off);
        if (e == 0) {
            if (n > 1) atomicAdd(pen_sum, contrib / (safe * (float)EEXP));
            if (n > 0) atomicAdd(uniq, 1.0f);
        }
    }
    __syncthreads();
    if (t == 0) {
        __threadfence();
        const int prev = atomicAdd(done_count, 1);
        if (prev == NDOCS - 1) {
            __threadfence();
            pen_out[0] = pen_sum[0] / uniq[0];
        }
    }
}

extern "C" void kernel_launch(void* const* d_in, const int* in_sizes, int n_in,
                              void* d_out, int out_size, void* d_ws, size_t ws_size,
                              hipStream_t stream) {
    const float* x   = (const float*)d_in[0];
    const int*   idx = (const int*)d_in[1];
    const float* Wg  = (const float*)d_in[2];

    float* out   = (float*)d_out;
    float* w_out = out;                                  // NROWS*EEXP floats
    float* pen   = out + (size_t)NROWS * EEXP;           // 1 float

    ushort_t* Wf     = (ushort_t*)d_ws;                  // 131072 ushorts
    int* hist_slices = (int*)(Wf + 131072);              // HB*NDOCS ints
    int* sorted_rows = hist_slices + HB * NDOCS;
    int* offsets     = sorted_rows + NROWS;
    int* cursor      = offsets + NDOCS + 1;
    float* pen_sum   = (float*)(cursor + NDOCS);
    float* uniq      = pen_sum + 1;
    int* done_count  = (int*)(uniq + 1);

    conv_hist_kernel<<<512 + HB, 256, 0, stream>>>(Wg, Wf, idx, hist_slices);
    scan_kernel<<<1, 1024, 0, stream>>>(hist_slices, offsets, cursor, pen_sum, uniq, done_count);
    gemm_scatter_kernel<<<NGEMM + HB, 256, 0, stream>>>(x, Wf, idx, cursor, sorted_rows, w_out);
    segsum_final_kernel<<<NDOCS, 256, 0, stream>>>(w_out, sorted_rows, offsets, pen_sum, uniq, done_count, pen);
}